// Round 1
// baseline (627.560 us; speedup 1.0000x reference)
//
#include <hip/hip_runtime.h>
#include <math.h>

#define H 4096
#define E 8

// ---------------------------------------------------------------------------
// Kernel A: router. One block, 8 waves; wave e computes logit e; thread 0 does
// first-max-wins argmax (matches jnp.argmax) and publishes idx to workspace.
// ~3-5 us (128 KB cold read), runs while nothing else could proceed anyway.
// ---------------------------------------------------------------------------
__global__ __launch_bounds__(512) void router_kernel(
    const float* __restrict__ x,
    const float* __restrict__ router_w,
    const float* __restrict__ router_b,
    int* __restrict__ idx_out)
{
    __shared__ float logits[E];
    const int wave = threadIdx.x >> 6;
    const int lane = threadIdx.x & 63;

    const float4* rw = (const float4*)(router_w + wave * H);
    const float4* x4 = (const float4*)x;
    float acc = 0.f;
#pragma unroll
    for (int k = 0; k < 16; ++k) {
        const int i = k * 64 + lane;
        float4 a  = rw[i];
        float4 xv = x4[i];
        acc += a.x * xv.x + a.y * xv.y + a.z * xv.z + a.w * xv.w;
    }
#pragma unroll
    for (int off = 32; off > 0; off >>= 1)
        acc += __shfl_down(acc, off, 64);
    if (lane == 0) logits[wave] = acc + router_b[wave];
    __syncthreads();

    if (threadIdx.x == 0) {
        int best = 0;
        float bv = logits[0];
#pragma unroll
        for (int e = 1; e < E; ++e)
            if (logits[e] > bv) { bv = logits[e]; best = e; }
        *idx_out = best;
    }
}

// ---------------------------------------------------------------------------
// Kernel B: dual GEMV + combine. 512 blocks x 512 threads; wave w of block b
// owns row j = b*8 + w. Gate row and expert row are streamed INTERLEAVED in a
// single loop (no data-dependent barrier anywhere; only the x-staging sync).
// Traffic: 134 MB -> ~21 us roofline.
// ---------------------------------------------------------------------------
__global__ __launch_bounds__(512) void moe_main_kernel(
    const float* __restrict__ x,
    const float* __restrict__ expert_w,
    const float* __restrict__ expert_b,
    const float* __restrict__ gate_w,
    const float* __restrict__ gate_b,
    const int* __restrict__ idx_in,
    float* __restrict__ out)
{
    __shared__ float4 xs[H / 4];   // 16 KB staged x

    const int tid  = threadIdx.x;
    const int wave = tid >> 6;
    const int lane = tid & 63;

    // Stage x into LDS (1024 float4 over 512 threads).
    const float4* x4 = (const float4*)x;
#pragma unroll
    for (int k = 0; k < 2; ++k)
        xs[k * 512 + tid] = x4[k * 512 + tid];

    // Uniform scalar load of the expert index; latency overlaps x staging.
    const int idx = *idx_in;
    __syncthreads();

    const int j = blockIdx.x * 8 + wave;

    const float4* gr = (const float4*)(gate_w + (size_t)j * H);
    const float4* er = (const float4*)(expert_w + ((size_t)idx * H + (size_t)j) * H);

    float acc_g = 0.f, acc_e = 0.f;
#pragma unroll
    for (int k = 0; k < 16; ++k) {
        const int i = k * 64 + lane;
        float4 gv = gr[i];
        float4 ev = er[i];
        float4 xv = xs[i];
        acc_g += gv.x * xv.x + gv.y * xv.y + gv.z * xv.z + gv.w * xv.w;
        acc_e += ev.x * xv.x + ev.y * xv.y + ev.z * xv.z + ev.w * xv.w;
    }

#pragma unroll
    for (int off = 32; off > 0; off >>= 1) {
        acc_g += __shfl_down(acc_g, off, 64);
        acc_e += __shfl_down(acc_e, off, 64);
    }

    if (lane == 0) {
        const float mix  = tanhf(acc_e + expert_b[(size_t)idx * H + j]);
        const float g    = 1.f / (1.f + expf(-(acc_g + gate_b[j])));
        const float xj   = ((const float*)xs)[j];
        out[j] = g * mix + (1.f - g) * xj;
    }
}

extern "C" void kernel_launch(void* const* d_in, const int* in_sizes, int n_in,
                              void* d_out, int out_size, void* d_ws, size_t ws_size,
                              hipStream_t stream) {
    const float* x        = (const float*)d_in[0];
    const float* expert_w = (const float*)d_in[1];
    const float* expert_b = (const float*)d_in[2];
    const float* router_w = (const float*)d_in[3];
    const float* router_b = (const float*)d_in[4];
    const float* gate_w   = (const float*)d_in[5];
    const float* gate_b   = (const float*)d_in[6];
    float* out = (float*)d_out;
    int* idx_ws = (int*)d_ws;

    router_kernel<<<1, 512, 0, stream>>>(x, router_w, router_b, idx_ws);
    moe_main_kernel<<<H / 8, 512, 0, stream>>>(
        x, expert_w, expert_b, gate_w, gate_b, idx_ws, out);
}